// Round 1
// baseline (123.515 us; speedup 1.0000x reference)
//
#include <hip/hip_runtime.h>
#include <stdint.h>
#include <stddef.h>

// Problem constants (reference: M=16, K=8192, N=8192, GROUP=128)
#define MM 16
#define KK 8192
#define NN 8192
#define GROUP_SZ 128
#define NGROUP 64            // K / GROUP
#define KPACK 1024           // K / 8 packed int32 per output row
#define SPLITK 8
#define KCH (KK / SPLITK)    // 1024 k per wave
#define GPW (KCH / GROUP_SZ) // 8 groups per wave

typedef _Float16 half8_t __attribute__((ext_vector_type(8)));
typedef float float4_t __attribute__((ext_vector_type(4)));
typedef uint32_t uint4_t __attribute__((ext_vector_type(4)));

// ---------------------------------------------------------------------------
// PRE1: x fp32 -> fp16, permuted within each 8-chunk by {0,4,1,5,2,6,3,7}
// (matches the nibble-unpack order of the fp16 dequant trick so A and B
// fragments pair up slot-for-slot inside the MFMA)
// ---------------------------------------------------------------------------
__global__ void pre_convert_x(const float* __restrict__ x,
                              _Float16* __restrict__ xh) {
    int i = blockIdx.x * blockDim.x + threadIdx.x;   // 0 .. 16*8192-1
    int slot = i & 7;
    int base = i & ~7;
    // perm[slot] = {0,4,1,5,2,6,3,7}
    int src = base + ((slot >> 1) | ((slot & 1) << 2));
    xh[i] = (_Float16)x[src];
}

// ---------------------------------------------------------------------------
// PRE2: per-(row,group) sums of the fp16 x values: sxg[m][g] = sum_{k in g} xh
// (must use the *fp16* values so the 1024-offset cancellation is exact)
// ---------------------------------------------------------------------------
__global__ void pre_group_sums(const _Float16* __restrict__ xh,
                               float* __restrict__ sxg) {
    int i = blockIdx.x * blockDim.x + threadIdx.x;   // 0..1023: m=i>>6, g=i&63
    int m = i >> 6, g = i & 63;
    const _Float16* p = xh + (size_t)m * KK + g * GROUP_SZ;
    float s = 0.f;
    #pragma unroll 8
    for (int k = 0; k < GROUP_SZ; ++k) s += (float)p[k];
    sxg[i] = s;
}

// ---------------------------------------------------------------------------
// PRE3: out[m][n] = bias[n] + sum_g (z[g,n] - 1024*s[g,n]) * sxg[m][g]
// Exact fp32 zero-point + bias init; main kernel atomicAdds on top.
// ---------------------------------------------------------------------------
__global__ __launch_bounds__(256) void pre_out_init(
        const float* __restrict__ scales, const float* __restrict__ zeros,
        const float* __restrict__ bias, const float* __restrict__ sxg,
        float* __restrict__ out) {
    __shared__ float lsxg[MM * NGROUP];  // 4 KB
    int t = threadIdx.x;
    for (int i = t; i < MM * NGROUP; i += 256) lsxg[i] = sxg[i];
    __syncthreads();
    int n = blockIdx.x * 256 + t;
    float b = bias[n];
    float acc[MM];
    #pragma unroll
    for (int m = 0; m < MM; ++m) acc[m] = b;
    for (int g = 0; g < NGROUP; ++g) {
        float s = scales[(size_t)g * NN + n];
        float z = zeros[(size_t)g * NN + n];
        float c = z - 1024.0f * s;
        #pragma unroll
        for (int m = 0; m < MM; ++m) acc[m] += c * lsxg[m * NGROUP + g];
    }
    #pragma unroll
    for (int m = 0; m < MM; ++m) out[(size_t)m * NN + n] = acc[m];
}

// ---------------------------------------------------------------------------
// MAIN: per wave, one 16-column n-tile x one K/8 slice.
// B lane fragment: one int32 of qweight -> 8 fp16 values (1024+q) via
// and/shift/or only. Per-group fp32 accumulator; out += s * gacc.
// ---------------------------------------------------------------------------
__global__ __launch_bounds__(256) void wq_main(
        const int* __restrict__ qweight,
        const float* __restrict__ scales,
        const _Float16* __restrict__ xh,
        float* __restrict__ out) {
    const int wid   = blockIdx.x * 4 + (threadIdx.x >> 6);
    const int lane  = threadIdx.x & 63;
    const int ntile = wid & (NN / 16 - 1);   // 512 n-tiles
    const int kc    = wid >> 9;              // 0..SPLITK-1
    const int nlo   = lane & 15;
    const int quad  = lane >> 4;
    const int n     = ntile * 16 + nlo;

    const int*      qrow = qweight + (size_t)n * KPACK;
    const _Float16* xrow = xh + (size_t)nlo * KK;   // A row m = lane&15

    float4_t outacc = {0.f, 0.f, 0.f, 0.f};
    const int k0 = kc * KCH;

    #pragma unroll 1
    for (int g = 0; g < GPW; ++g) {
        const int gk = k0 + g * GROUP_SZ;
        const int gg = gk >> 7;                       // global group index
        float s = scales[(size_t)gg * NN + n];

        uint32_t bw[4];
        half8_t  af[4];
        #pragma unroll
        for (int j = 0; j < 4; ++j) {
            // B: lane needs W[n][gk + j*32 + quad*8 .. +7] = one int32
            bw[j] = (uint32_t)qrow[(gk >> 3) + j * 4 + quad];
            // A: x_h[m][gk + j*32 + quad*8 .. +7], 16B aligned
            af[j] = __builtin_bit_cast(half8_t,
                      *(const float4_t*)(xrow + gk + j * 32 + quad * 8));
        }

        float4_t gacc = {0.f, 0.f, 0.f, 0.f};
        #pragma unroll
        for (int j = 0; j < 4; ++j) {
            const uint32_t d = bw[j];
            uint4_t bb;
            bb.x = ( d         & 0x000F000Fu) | 0x64006400u;  // 1024+q, slots (0,4)
            bb.y = ((d >> 4)   & 0x000F000Fu) | 0x64006400u;  // (1,5)
            bb.z = ((d >> 8)   & 0x000F000Fu) | 0x64006400u;  // (2,6)
            bb.w = ((d >> 12)  & 0x000F000Fu) | 0x64006400u;  // (3,7)
            gacc = __builtin_amdgcn_mfma_f32_16x16x32_f16(
                       af[j], __builtin_bit_cast(half8_t, bb), gacc, 0, 0, 0);
        }
        outacc += s * gacc;   // per-lane scalar: col n fixed per lane
    }

    // C/D layout: col = lane&15, row = quad*4 + reg
    #pragma unroll
    for (int r = 0; r < 4; ++r) {
        atomicAdd(&out[(size_t)(quad * 4 + r) * NN + n], outacc[r]);
    }
}

// ---------------------------------------------------------------------------
extern "C" void kernel_launch(void* const* d_in, const int* in_sizes, int n_in,
                              void* d_out, int out_size, void* d_ws, size_t ws_size,
                              hipStream_t stream) {
    const float* x      = (const float*)d_in[0];   // [16, 8192]
    const int*   qw     = (const int*)d_in[1];     // [8192, 1024]
    const float* scales = (const float*)d_in[2];   // [64, 8192]
    const float* zeros  = (const float*)d_in[3];   // [64, 8192]
    const float* bias   = (const float*)d_in[4];   // [8192]
    float* out = (float*)d_out;                    // [16, 8192] fp32

    // workspace: xh (16*8192 fp16 = 256KB) then sxg (16*64 fp32 = 4KB)
    _Float16* xh  = (_Float16*)d_ws;
    float*    sxg = (float*)((char*)d_ws + (size_t)MM * KK * sizeof(_Float16));

    pre_convert_x<<<(MM * KK) / 256, 256, 0, stream>>>(x, xh);
    pre_group_sums<<<(MM * NGROUP) / 256, 256, 0, stream>>>(xh, sxg);
    pre_out_init<<<NN / 256, 256, 0, stream>>>(scales, zeros, bias, sxg, out);
    // 512 n-tiles * SPLITK waves, 4 waves per block
    wq_main<<<(NN / 16) * SPLITK / 4, 256, 0, stream>>>(qw, scales, xh, out);
}

// Round 2
// 104.518 us; speedup vs baseline: 1.1818x; 1.1818x over previous
//
#include <hip/hip_runtime.h>
#include <stdint.h>
#include <stddef.h>

// Problem constants (reference: M=16, K=8192, N=8192, GROUP=128)
#define MM 16
#define KK 8192
#define NN 8192
#define GROUP_SZ 128
#define NGROUP 64            // K / GROUP
#define KPACK 1024           // K / 8 packed int32 per output row
#define SPLITK 8
#define KCH (KK / SPLITK)    // 1024 k per wave
#define GPW (KCH / GROUP_SZ) // 8 groups per wave

typedef _Float16 half8_t __attribute__((ext_vector_type(8)));
typedef float float4_t __attribute__((ext_vector_type(4)));
typedef uint32_t uint4_t __attribute__((ext_vector_type(4)));

// ---------------------------------------------------------------------------
// PRE: x fp32 -> fp16 permuted within each 8-chunk by {0,4,1,5,2,6,3,7}
// (matches nibble-unpack slot order), FUSED with per-(m,group) sums of the
// fp16 values (block covers exactly 2 groups: 256 contiguous elements).
// ---------------------------------------------------------------------------
__global__ __launch_bounds__(256) void pre_x(const float* __restrict__ x,
                                             _Float16* __restrict__ xh,
                                             float* __restrict__ sxg) {
    const int i = blockIdx.x * 256 + threadIdx.x;   // 0 .. 16*8192-1
    const int slot = i & 7;
    const int base = i & ~7;
    const int src = base + ((slot >> 1) | ((slot & 1) << 2)); // {0,4,1,5,2,6,3,7}
    const float v = x[src];
    const _Float16 h = (_Float16)v;
    xh[i] = h;

    // group sum of the fp16-rounded values (exact 1024-term cancellation)
    float f = (float)h;
    #pragma unroll
    for (int off = 32; off > 0; off >>= 1) f += __shfl_down(f, off);
    __shared__ float part[4];
    if ((threadIdx.x & 63) == 0) part[threadIdx.x >> 6] = f;
    __syncthreads();
    // block covers (m,g) cells 2b and 2b+1 (each 128 contiguous elements)
    if (threadIdx.x == 0) sxg[blockIdx.x * 2]     = part[0] + part[1];
    if (threadIdx.x == 1) sxg[blockIdx.x * 2 + 1] = part[2] + part[3];
}

// ---------------------------------------------------------------------------
// MAIN: per wave, one 16-column n-tile x one K/8 slice.
// qweight: one dwordx4 per lane per group (quad*4 packed words = k-chunk
// quad*32..quad*32+31). A-fragment indexed with the matching (quad,j) swap so
// A/B stay k-consistent positionally inside each MFMA.
// Epilogue folds scale, zero-point correction (via sxg in LDS) and bias
// (kc==0 waves only); atomicAdd into memset-zeroed out.
// ---------------------------------------------------------------------------
__global__ __launch_bounds__(256) void wq_main(
        const int* __restrict__ qweight,
        const float* __restrict__ scales,
        const float* __restrict__ zeros,
        const float* __restrict__ bias,
        const _Float16* __restrict__ xh,
        const float* __restrict__ sxg,
        float* __restrict__ out) {
    __shared__ float lsxg[MM * NGROUP];  // 4 KB
    {
        const int t = threadIdx.x;
        #pragma unroll
        for (int i = 0; i < 4; ++i) lsxg[i * 256 + t] = sxg[i * 256 + t];
    }
    __syncthreads();

    const int wid   = blockIdx.x * 4 + (threadIdx.x >> 6);
    const int lane  = threadIdx.x & 63;
    const int ntile = wid & (NN / 16 - 1);   // 512 n-tiles
    const int kc    = wid >> 9;              // 0..SPLITK-1
    const int nlo   = lane & 15;
    const int quad  = lane >> 4;
    const int n     = ntile * 16 + nlo;

    const int*      qrow = qweight + (size_t)n * KPACK;
    const _Float16* xrow = xh + (size_t)nlo * KK;   // A row m = lane&15

    float4_t outacc = {0.f, 0.f, 0.f, 0.f};
    if (kc == 0) {
        const float b = bias[n];
        outacc[0] = b; outacc[1] = b; outacc[2] = b; outacc[3] = b;
    }
    const int k0 = kc * KCH;

    #pragma unroll 2
    for (int g = 0; g < GPW; ++g) {
        const int gk = k0 + g * GROUP_SZ;
        const int gg = gk >> 7;                       // global group index
        const float s = scales[(size_t)gg * NN + n];
        const float z = zeros[(size_t)gg * NN + n];

        // B: 16B = 4 packed int32 = k-chunk [gk + quad*32, +32)
        const uint4_t bw = *(const uint4_t*)(qrow + (gk >> 3) + quad * 4);
        // A: matching k-chunks, 16B each
        half8_t af[4];
        #pragma unroll
        for (int j = 0; j < 4; ++j)
            af[j] = __builtin_bit_cast(half8_t,
                      *(const float4_t*)(xrow + gk + quad * 32 + j * 8));

        float4_t gacc = {0.f, 0.f, 0.f, 0.f};
        #pragma unroll
        for (int j = 0; j < 4; ++j) {
            const uint32_t d = bw[j];
            uint4_t bb;
            bb.x = ( d         & 0x000F000Fu) | 0x64006400u;  // 1024+q, nibbles (0,4)
            bb.y = ((d >> 4)   & 0x000F000Fu) | 0x64006400u;  // (1,5)
            bb.z = ((d >> 8)   & 0x000F000Fu) | 0x64006400u;  // (2,6)
            bb.w = ((d >> 12)  & 0x000F000Fu) | 0x64006400u;  // (3,7)
            gacc = __builtin_amdgcn_mfma_f32_16x16x32_f16(
                       af[j], __builtin_bit_cast(half8_t, bb), gacc, 0, 0, 0);
        }
        const float c = z - 1024.0f * s;
        #pragma unroll
        for (int r = 0; r < 4; ++r)
            outacc[r] += s * gacc[r] + c * lsxg[(quad * 4 + r) * NGROUP + gg];
    }

    // C/D layout: col = lane&15, row = quad*4 + reg
    #pragma unroll
    for (int r = 0; r < 4; ++r) {
        atomicAdd(&out[(size_t)(quad * 4 + r) * NN + n], outacc[r]);
    }
}

// ---------------------------------------------------------------------------
extern "C" void kernel_launch(void* const* d_in, const int* in_sizes, int n_in,
                              void* d_out, int out_size, void* d_ws, size_t ws_size,
                              hipStream_t stream) {
    const float* x      = (const float*)d_in[0];   // [16, 8192]
    const int*   qw     = (const int*)d_in[1];     // [8192, 1024]
    const float* scales = (const float*)d_in[2];   // [64, 8192]
    const float* zeros  = (const float*)d_in[3];   // [64, 8192]
    const float* bias   = (const float*)d_in[4];   // [8192]
    float* out = (float*)d_out;                    // [16, 8192] fp32

    // workspace: xh (16*8192 fp16 = 256KB) then sxg (16*64 fp32 = 4KB)
    _Float16* xh  = (_Float16*)d_ws;
    float*    sxg = (float*)((char*)d_ws + (size_t)MM * KK * sizeof(_Float16));

    hipMemsetAsync(out, 0, (size_t)MM * NN * sizeof(float), stream);
    pre_x<<<(MM * KK) / 256, 256, 0, stream>>>(x, xh, sxg);
    // 512 n-tiles * SPLITK waves, 4 waves per block
    wq_main<<<(NN / 16) * SPLITK / 4, 256, 0, stream>>>(
        qw, scales, zeros, bias, xh, sxg, out);
}

// Round 3
// 96.043 us; speedup vs baseline: 1.2860x; 1.0882x over previous
//
#include <hip/hip_runtime.h>
#include <stdint.h>
#include <stddef.h>

// Problem constants (reference: M=16, K=8192, N=8192, GROUP=128)
#define MM 16
#define KK 8192
#define NN 8192
#define GROUP_SZ 128
#define NGROUP 64            // K / GROUP
#define KPACK 1024           // K / 8 packed int32 per output row
#define NWAVE 8              // waves per wq_main block (one K/8 slice each)
#define KCH (KK / NWAVE)     // 1024 k per wave
#define GPW (KCH / GROUP_SZ) // 8 groups per wave

typedef _Float16 half8_t __attribute__((ext_vector_type(8)));
typedef float float4_t __attribute__((ext_vector_type(4)));
typedef uint32_t uint4_t __attribute__((ext_vector_type(4)));

// ---------------------------------------------------------------------------
// PRE (one launch, 528 blocks):
//  blocks 0..511  : pack x (fp32) into fp16 MFMA-A-fragment order:
//                   xf[(((g*4 + j)*64 + lane)*8 + slot)] =
//                     fp16( x[m = lane&15][ g*128 + (lane>>4)*32 + j*8 + perm[slot] ] )
//                   perm = {0,4,1,5,2,6,3,7} (nibble-unpack slot order).
//                   -> wq_main's A-loads become fully coalesced dwordx4.
//  blocks 512..527: exact per-(m,group) sums of the fp16-rounded x values
//                   (needed for the fp32 zero-point correction; must use the
//                   SAME rounded values so the 1024-offset cancels exactly).
// ---------------------------------------------------------------------------
__global__ __launch_bounds__(256) void pre_x(const float* __restrict__ x,
                                             _Float16* __restrict__ xf,
                                             float* __restrict__ sxg) {
    const int b = blockIdx.x;
    if (b < 512) {
        const int i    = b * 256 + threadIdx.x;   // 0 .. 16*8192-1 (xf index)
        const int slot = i & 7;
        const int L    = (i >> 3) & 63;
        const int j    = (i >> 9) & 3;
        const int g    = i >> 11;
        const int m    = L & 15;
        const int quad = L >> 4;
        const int p    = (slot >> 1) | ((slot & 1) << 2);  // perm[slot]
        const int k    = g * GROUP_SZ + quad * 32 + j * 8 + p;
        xf[i] = (_Float16)x[m * KK + k];
    } else {
        const int m = b - 512;
        const int t = threadIdx.x;                 // covers k [t*32, t*32+32)
        const float4_t* xr = (const float4_t*)(x + (size_t)m * KK + t * 32);
        float s = 0.f;
        #pragma unroll
        for (int u = 0; u < 8; ++u) {
            float4_t v = xr[u];
            s += (float)(_Float16)v[0] + (float)(_Float16)v[1]
               + (float)(_Float16)v[2] + (float)(_Float16)v[3];
        }
        // 4 consecutive lanes = one group (128 k): cluster reduce
        s += __shfl_down(s, 2, 64);
        s += __shfl_down(s, 1, 64);
        if ((t & 3) == 0) sxg[m * NGROUP + (t >> 2)] = s;
    }
}

// ---------------------------------------------------------------------------
// MAIN: 512 blocks (one per 16-col n-tile) x 512 threads (8 waves).
// Wave w owns k-slice [w*1024, (w+1)*1024) = 8 groups.
//   qweight: one coalesced-ish dwordx4 per lane per group (lines fully used).
//   A: one fully-coalesced dwordx4 per lane per (group, j) from xf.
//   Dequant: (d>>4j & 0x000F000F) | 0x64006400 -> fp16 (1024+q); fp32 group
//   accumulator; epilogue folds scale + exact zero-point correction via sxg.
// Cross-wave LDS reduce -> direct store with bias. No atomics, no memset.
// ---------------------------------------------------------------------------
__global__ __launch_bounds__(512) void wq_main(
        const int* __restrict__ qweight,
        const float* __restrict__ scales,
        const float* __restrict__ zeros,
        const float* __restrict__ bias,
        const _Float16* __restrict__ xf,
        const float* __restrict__ sxg,
        float* __restrict__ out) {
    __shared__ float red[NWAVE * 256];   // 8 KB: per-wave 16x16 partial tiles
    __shared__ float lsxg[MM * NGROUP];  // 4 KB

    const int t = threadIdx.x;
    lsxg[t]       = sxg[t];
    lsxg[t + 512] = sxg[t + 512];
    __syncthreads();

    const int w     = t >> 6;
    const int lane  = t & 63;
    const int ntile = blockIdx.x;
    const int nlo   = lane & 15;
    const int quad  = lane >> 4;
    const int n     = ntile * 16 + nlo;

    // this wave's qweight slice: row n, ints [w*128, w*128+128)
    const int* qrow = qweight + (size_t)n * KPACK + w * (KCH / 8);

    float4_t outacc = {0.f, 0.f, 0.f, 0.f};
    const int g0 = w * GPW;

    #pragma unroll 2
    for (int g = 0; g < GPW; ++g) {
        const int gg  = g0 + g;
        const float s = scales[(size_t)gg * NN + n];
        const float z = zeros[(size_t)gg * NN + n];

        // B: 16B = 4 packed int32 = k-chunk [gk + quad*32, +32)
        const uint4_t bw = *(const uint4_t*)(qrow + g * 16 + quad * 4);
        // A: fragment-ordered, lane-consecutive 16B -> fully coalesced
        half8_t af[4];
        #pragma unroll
        for (int j = 0; j < 4; ++j)
            af[j] = *(const half8_t*)(xf + ((size_t)gg * 256 + j * 64 + lane) * 8);

        float4_t gacc = {0.f, 0.f, 0.f, 0.f};
        #pragma unroll
        for (int j = 0; j < 4; ++j) {
            const uint32_t d = bw[j];
            uint4_t bb;
            bb.x = ( d         & 0x000F000Fu) | 0x64006400u;  // nibbles (0,4)
            bb.y = ((d >> 4)   & 0x000F000Fu) | 0x64006400u;  // (1,5)
            bb.z = ((d >> 8)   & 0x000F000Fu) | 0x64006400u;  // (2,6)
            bb.w = ((d >> 12)  & 0x000F000Fu) | 0x64006400u;  // (3,7)
            gacc = __builtin_amdgcn_mfma_f32_16x16x32_f16(
                       af[j], __builtin_bit_cast(half8_t, bb), gacc, 0, 0, 0);
        }
        const float c = z - 1024.0f * s;
        #pragma unroll
        for (int r = 0; r < 4; ++r)
            outacc[r] += s * gacc[r] + c * lsxg[(quad * 4 + r) * NGROUP + gg];
    }

    // C/D layout: col = lane&15, row = quad*4 + r  -> red[w][row*16 + col]
    #pragma unroll
    for (int r = 0; r < 4; ++r)
        red[w * 256 + (quad * 4 + r) * 16 + nlo] = outacc[r];
    __syncthreads();

    if (t < 256) {
        const int m  = t >> 4;
        const int nn = t & 15;
        float v = bias[ntile * 16 + nn];
        #pragma unroll
        for (int ww = 0; ww < NWAVE; ++ww) v += red[ww * 256 + t];
        out[(size_t)m * NN + ntile * 16 + nn] = v;
    }
}

// ---------------------------------------------------------------------------
extern "C" void kernel_launch(void* const* d_in, const int* in_sizes, int n_in,
                              void* d_out, int out_size, void* d_ws, size_t ws_size,
                              hipStream_t stream) {
    const float* x      = (const float*)d_in[0];   // [16, 8192]
    const int*   qw     = (const int*)d_in[1];     // [8192, 1024]
    const float* scales = (const float*)d_in[2];   // [64, 8192]
    const float* zeros  = (const float*)d_in[3];   // [64, 8192]
    const float* bias   = (const float*)d_in[4];   // [8192]
    float* out = (float*)d_out;                    // [16, 8192] fp32

    // workspace: xf (16*8192 fp16 = 256KB, fragment-ordered) then sxg (4KB)
    _Float16* xf  = (_Float16*)d_ws;
    float*    sxg = (float*)((char*)d_ws + (size_t)MM * KK * sizeof(_Float16));

    pre_x<<<512 + MM, 256, 0, stream>>>(x, xf, sxg);
    wq_main<<<NN / 16, 512, 0, stream>>>(qw, scales, zeros, bias, xf, sxg, out);
}